// Round 1
// baseline (136.984 us; speedup 1.0000x reference)
//
#include <hip/hip_runtime.h>
#include <hip/hip_bf16.h>

typedef short short8 __attribute__((ext_vector_type(8)));
typedef float floatx4 __attribute__((ext_vector_type(4)));

#define HID 32
#define NTD 8
#define FAN_IN 18

// round-to-nearest-even f32 -> bf16 (bit pattern in a short)
__device__ __forceinline__ short f2bf(float f) {
    union { float f; unsigned u; } v; v.f = f;
    unsigned r = v.u + 0x7fffu + ((v.u >> 16) & 1u);
    return (short)(r >> 16);
}

__global__ __launch_bounds__(256, 4) void lg_kernel(
    const float* __restrict__ nt_emb,
    const char* __restrict__ ei_bytes,
    const float* __restrict__ lm_mask,
    const float* __restrict__ W1,
    const float* __restrict__ b1,
    const float* __restrict__ W2,
    const float* __restrict__ b2,
    float* __restrict__ out,
    long long E)
{
    const int lane = threadIdx.x & 63;
    const int waveInBlock = threadIdx.x >> 6;
    const long long waveId = (long long)blockIdx.x * (blockDim.x >> 6) + waveInBlock;
    const long long nWaves = (long long)gridDim.x * (blockDim.x >> 6);

    // --- detect edge_index element size: int64 (odd 4B words all zero) vs int32 ---
    const int* ei32 = (const int*)ei_bytes;
    int probe = ei32[2 * lane + 1];
    unsigned long long nz = __ballot(probe != 0);
    const long long esz = (nz == 0ull) ? 8 : 4;

    const int r = lane & 15;   // A row / B col / edge-in-group
    const int g = lane >> 4;   // lane group -> k-slice g*8 .. g*8+7

    // --- A fragments: A[row][k] = W1[k][row]; k==18 carries b1 (bias-as-feature) ---
    short8 a0, a1;
    #pragma unroll
    for (int j = 0; j < 8; ++j) {
        int k = g * 8 + j;
        float v0 = 0.f, v1 = 0.f;
        if (k < FAN_IN)       { v0 = W1[k * HID + r];      v1 = W1[k * HID + 16 + r]; }
        else if (k == FAN_IN) { v0 = b1[r];                v1 = b1[16 + r]; }
        a0[j] = f2bf(v0);
        a1[j] = f2bf(v1);
    }

    // W2 entries for the C rows this lane owns: row = g*4 + q (+16 for acc1)
    float w2v0[4], w2v1[4];
    #pragma unroll
    for (int q = 0; q < 4; ++q) {
        w2v0[q] = W2[g * 4 + q];
        w2v1[q] = W2[16 + g * 4 + q];
    }
    const float bias2 = b2[0];

    const long long nGroups = (E + 15) >> 4;
    for (long long grp = waveId; grp < nGroups; grp += nWaves) {
        long long e = (grp << 4) + r;
        const bool valid = (e < E);
        long long ec = valid ? e : (E - 1);

        int s = *(const int*)(ei_bytes + ec * esz);
        int d = *(const int*)(ei_bytes + (E + ec) * esz);

        short8 fb;
        #pragma unroll
        for (int j = 0; j < 8; ++j) fb[j] = 0;
        if (g < 2) {
            const float4* p = (const float4*)(nt_emb + (long long)(g == 0 ? s : d) * NTD);
            float4 lo = p[0];
            float4 hi = p[1];
            fb[0] = f2bf(lo.x); fb[1] = f2bf(lo.y); fb[2] = f2bf(lo.z); fb[3] = f2bf(lo.w);
            fb[4] = f2bf(hi.x); fb[5] = f2bf(hi.y); fb[6] = f2bf(hi.z); fb[7] = f2bf(hi.w);
        } else if (g == 2) {
            fb[0] = f2bf(lm_mask[s]);   // k=16: src mask
            fb[1] = f2bf(lm_mask[d]);   // k=17: dst mask
            fb[2] = (short)0x3F80;      // k=18: constant 1.0 -> bias row of A
        }
        // g == 3: zeros (k=24..31 padding)

        floatx4 acc0 = {0.f, 0.f, 0.f, 0.f};
        floatx4 acc1 = {0.f, 0.f, 0.f, 0.f};
        acc0 = __builtin_amdgcn_mfma_f32_16x16x32_bf16(a0, fb, acc0, 0, 0, 0);
        acc1 = __builtin_amdgcn_mfma_f32_16x16x32_bf16(a1, fb, acc1, 0, 0, 0);

        // epilogue: relu + W2 dot (this lane holds hid rows g*4+q and 16+g*4+q for edge r)
        float partial = 0.f;
        #pragma unroll
        for (int q = 0; q < 4; ++q) {
            partial += fmaxf(acc0[q], 0.f) * w2v0[q];
            partial += fmaxf(acc1[q], 0.f) * w2v1[q];
        }
        partial += __shfl_xor(partial, 16, 64);
        partial += __shfl_xor(partial, 32, 64);

        float val = 1.0f / (1.0f + __expf(-(partial + bias2)));
        if (g == 0 && valid) out[e] = val;
    }
}

extern "C" void kernel_launch(void* const* d_in, const int* in_sizes, int n_in,
                              void* d_out, int out_size, void* d_ws, size_t ws_size,
                              hipStream_t stream) {
    const float* nt_emb = (const float*)d_in[0];
    const char*  ei     = (const char*)d_in[1];
    const float* lm     = (const float*)d_in[2];
    const float* W1     = (const float*)d_in[3];
    const float* b1     = (const float*)d_in[4];
    const float* W2     = (const float*)d_in[5];
    const float* b2     = (const float*)d_in[6];
    float* out = (float*)d_out;

    long long E = (long long)in_sizes[1] / 2;   // edge_index is [2, E]

    const int blocks = 2048;   // 8192 waves, grid-stride over 400K 16-edge groups
    lg_kernel<<<dim3(blocks), dim3(256), 0, stream>>>(nt_emb, ei, lm, W1, b1, W2, b2, out, E);
}

// Round 2
// 82.621 us; speedup vs baseline: 1.6580x; 1.6580x over previous
//
#include <hip/hip_runtime.h>
#include <hip/hip_bf16.h>

typedef short short8 __attribute__((ext_vector_type(8)));
typedef float floatx4 __attribute__((ext_vector_type(4)));

#define HID 32
#define NTD 8
#define FAN_IN 18

// round-to-nearest-even f32 -> bf16 (bit pattern in a short)
__device__ __forceinline__ short f2bf(float f) {
    union { float f; unsigned u; } v; v.f = f;
    unsigned r = v.u + 0x7fffu + ((v.u >> 16) & 1u);
    return (short)(r >> 16);
}

// ---------------- table build: T[n] = [emb(8), mask, 1.0, 0x6] as 16 bf16 (32B/row)
__global__ void build_table(const float* __restrict__ emb,
                            const float* __restrict__ mask,
                            short* __restrict__ T, int N) {
    int n = blockIdx.x * blockDim.x + threadIdx.x;
    if (n >= N) return;
    const float4* p = (const float4*)(emb + (size_t)n * NTD);
    float4 lo = p[0], hi = p[1];
    short8 a, b;
    a[0] = f2bf(lo.x); a[1] = f2bf(lo.y); a[2] = f2bf(lo.z); a[3] = f2bf(lo.w);
    a[4] = f2bf(hi.x); a[5] = f2bf(hi.y); a[6] = f2bf(hi.z); a[7] = f2bf(hi.w);
    b[0] = f2bf(mask[n]); b[1] = (short)0x3F80;  // 1.0 bf16 (bias carrier)
    b[2] = b[3] = b[4] = b[5] = b[6] = b[7] = 0;
    short8* row = (short8*)(T + (size_t)n * 16);
    row[0] = a; row[1] = b;
}

// ---------------- main kernel (table path) ----------------
template <int ESZ>
__device__ __forceinline__ void load_idx(const char* __restrict__ sideBase,
                                         long long base, long long E, int r,
                                         int idx[4]) {
    long long e0 = base + 4 * r;
    if (base + 64 <= E) {
        if (ESZ == 8) {
            const int4* ip = (const int4*)(sideBase + e0 * 8);
            int4 w0 = ip[0], w1 = ip[1];
            idx[0] = w0.x; idx[1] = w0.z; idx[2] = w1.x; idx[3] = w1.z;
        } else {
            int4 w0 = *(const int4*)(sideBase + e0 * 4);
            idx[0] = w0.x; idx[1] = w0.y; idx[2] = w0.z; idx[3] = w0.w;
        }
    } else {
        #pragma unroll
        for (int t = 0; t < 4; ++t) {
            long long e = e0 + t;
            if (e >= E) e = E - 1;
            idx[t] = *(const int*)(sideBase + e * ESZ);
        }
    }
}

template <int ESZ>
__device__ void run_loop(const char* __restrict__ ei,
                         const short* __restrict__ T,
                         float* __restrict__ out, long long E,
                         short8 a0, short8 a1,
                         const float* w2v0, const float* w2v1, float bias2,
                         long long waveId, long long nWaves, int g, int r) {
    const long long nGroups = (E + 63) >> 6;
    // g=0: s-row bytes 0..15 (k=0..7), g=1: s-row 16..31 (k=8..15)
    // g=2: d-row bytes 0..15 (k=16..23), g=3: d-row 16..31 (k=24..31)
    const char* sideBase = ei + (g >= 2 ? (size_t)E * ESZ : 0);
    const int halfOff = (g & 1) * 16;

    long long grp = waveId;
    int idx[4] = {0, 0, 0, 0};
    if (grp < nGroups) load_idx<ESZ>(sideBase, grp << 6, E, r, idx);

    while (grp < nGroups) {
        const long long base = grp << 6;
        const long long nxt = grp + nWaves;

        // gathers for current group (B-fragments, direct from bf16 table)
        short8 fb0 = *(const short8*)((const char*)T + (size_t)(unsigned)idx[0] * 32 + halfOff);
        short8 fb1 = *(const short8*)((const char*)T + (size_t)(unsigned)idx[1] * 32 + halfOff);
        short8 fb2 = *(const short8*)((const char*)T + (size_t)(unsigned)idx[2] * 32 + halfOff);
        short8 fb3 = *(const short8*)((const char*)T + (size_t)(unsigned)idx[3] * 32 + halfOff);

        // prefetch next group's indices (independent of the gathers above)
        int idxn[4] = {0, 0, 0, 0};
        if (nxt < nGroups) load_idx<ESZ>(sideBase, nxt << 6, E, r, idxn);

        float vals[4];
        #pragma unroll
        for (int t = 0; t < 4; ++t) {
            short8 fb = (t == 0) ? fb0 : (t == 1) ? fb1 : (t == 2) ? fb2 : fb3;
            floatx4 acc0 = {0.f, 0.f, 0.f, 0.f};
            floatx4 acc1 = {0.f, 0.f, 0.f, 0.f};
            acc0 = __builtin_amdgcn_mfma_f32_16x16x32_bf16(a0, fb, acc0, 0, 0, 0);
            acc1 = __builtin_amdgcn_mfma_f32_16x16x32_bf16(a1, fb, acc1, 0, 0, 0);
            float partial = 0.f;
            #pragma unroll
            for (int q = 0; q < 4; ++q) {
                partial += fmaxf(acc0[q], 0.f) * w2v0[q];
                partial += fmaxf(acc1[q], 0.f) * w2v1[q];
            }
            partial += __shfl_xor(partial, 16, 64);
            partial += __shfl_xor(partial, 32, 64);
            vals[t] = 1.0f / (1.0f + __expf(-(partial + bias2)));
        }

        if (g == 0) {
            long long e0 = base + 4 * r;
            if (base + 64 <= E) {
                float4 v4 = {vals[0], vals[1], vals[2], vals[3]};
                *(float4*)(out + e0) = v4;
            } else {
                #pragma unroll
                for (int t = 0; t < 4; ++t)
                    if (e0 + t < E) out[e0 + t] = vals[t];
            }
        }

        idx[0] = idxn[0]; idx[1] = idxn[1]; idx[2] = idxn[2]; idx[3] = idxn[3];
        grp = nxt;
    }
}

__global__ __launch_bounds__(256, 4) void lg_table_kernel(
    const char* __restrict__ ei_bytes,
    const short* __restrict__ T,
    const float* __restrict__ W1,
    const float* __restrict__ b1,
    const float* __restrict__ W2,
    const float* __restrict__ b2,
    float* __restrict__ out,
    long long E)
{
    const int lane = threadIdx.x & 63;
    const int waveInBlock = threadIdx.x >> 6;
    const long long waveId = (long long)blockIdx.x * (blockDim.x >> 6) + waveInBlock;
    const long long nWaves = (long long)gridDim.x * (blockDim.x >> 6);

    // detect edge_index element size: int64 (odd 4B words all zero) vs int32
    const int* ei32 = (const int*)ei_bytes;
    int probe = ei32[2 * lane + 1];
    unsigned long long nz = __ballot(probe != 0);
    const int esz = (nz == 0ull) ? 8 : 4;

    const int r = lane & 15;   // A row / B col
    const int g = lane >> 4;   // k-slice g*8 .. g*8+7

    // A fragments: A[row][k] with feature map:
    //   k0..7 = emb_s -> W1[0..7], k8 = ms -> W1[16], k9 = 1 -> b1, k10..15 = 0
    //   k16..23 = emb_d -> W1[8..15], k24 = md -> W1[17], k25..31 = 0
    short8 a0, a1;
    #pragma unroll
    for (int j = 0; j < 8; ++j) {
        int k = g * 8 + j;
        float v0 = 0.f, v1 = 0.f;
        if (k < 8)                    { v0 = W1[k * HID + r];        v1 = W1[k * HID + 16 + r]; }
        else if (k == 8)              { v0 = W1[16 * HID + r];       v1 = W1[16 * HID + 16 + r]; }
        else if (k == 9)              { v0 = b1[r];                  v1 = b1[16 + r]; }
        else if (k >= 16 && k < 24)   { v0 = W1[(k - 8) * HID + r];  v1 = W1[(k - 8) * HID + 16 + r]; }
        else if (k == 24)             { v0 = W1[17 * HID + r];       v1 = W1[17 * HID + 16 + r]; }
        a0[j] = f2bf(v0);
        a1[j] = f2bf(v1);
    }

    float w2v0[4], w2v1[4];
    #pragma unroll
    for (int q = 0; q < 4; ++q) {
        w2v0[q] = W2[g * 4 + q];
        w2v1[q] = W2[16 + g * 4 + q];
    }
    const float bias2 = b2[0];

    if (esz == 8)
        run_loop<8>(ei_bytes, T, out, E, a0, a1, w2v0, w2v1, bias2, waveId, nWaves, g, r);
    else
        run_loop<4>(ei_bytes, T, out, E, a0, a1, w2v0, w2v1, bias2, waveId, nWaves, g, r);
}

// ---------------- fallback (round-1 kernel, used if d_ws too small) ----------------
__global__ __launch_bounds__(256, 4) void lg_kernel(
    const float* __restrict__ nt_emb,
    const char* __restrict__ ei_bytes,
    const float* __restrict__ lm_mask,
    const float* __restrict__ W1,
    const float* __restrict__ b1,
    const float* __restrict__ W2,
    const float* __restrict__ b2,
    float* __restrict__ out,
    long long E)
{
    const int lane = threadIdx.x & 63;
    const int waveInBlock = threadIdx.x >> 6;
    const long long waveId = (long long)blockIdx.x * (blockDim.x >> 6) + waveInBlock;
    const long long nWaves = (long long)gridDim.x * (blockDim.x >> 6);

    const int* ei32 = (const int*)ei_bytes;
    int probe = ei32[2 * lane + 1];
    unsigned long long nz = __ballot(probe != 0);
    const long long esz = (nz == 0ull) ? 8 : 4;

    const int r = lane & 15;
    const int g = lane >> 4;

    short8 a0, a1;
    #pragma unroll
    for (int j = 0; j < 8; ++j) {
        int k = g * 8 + j;
        float v0 = 0.f, v1 = 0.f;
        if (k < FAN_IN)       { v0 = W1[k * HID + r];      v1 = W1[k * HID + 16 + r]; }
        else if (k == FAN_IN) { v0 = b1[r];                v1 = b1[16 + r]; }
        a0[j] = f2bf(v0);
        a1[j] = f2bf(v1);
    }

    float w2v0[4], w2v1[4];
    #pragma unroll
    for (int q = 0; q < 4; ++q) {
        w2v0[q] = W2[g * 4 + q];
        w2v1[q] = W2[16 + g * 4 + q];
    }
    const float bias2 = b2[0];

    const long long nGroups = (E + 15) >> 4;
    for (long long grp = waveId; grp < nGroups; grp += nWaves) {
        long long e = (grp << 4) + r;
        const bool valid = (e < E);
        long long ec = valid ? e : (E - 1);

        int s = *(const int*)(ei_bytes + ec * esz);
        int d = *(const int*)(ei_bytes + (E + ec) * esz);

        short8 fb;
        #pragma unroll
        for (int j = 0; j < 8; ++j) fb[j] = 0;
        if (g < 2) {
            const float4* p = (const float4*)(nt_emb + (long long)(g == 0 ? s : d) * NTD);
            float4 lo = p[0];
            float4 hi = p[1];
            fb[0] = f2bf(lo.x); fb[1] = f2bf(lo.y); fb[2] = f2bf(lo.z); fb[3] = f2bf(lo.w);
            fb[4] = f2bf(hi.x); fb[5] = f2bf(hi.y); fb[6] = f2bf(hi.z); fb[7] = f2bf(hi.w);
        } else if (g == 2) {
            fb[0] = f2bf(lm_mask[s]);
            fb[1] = f2bf(lm_mask[d]);
            fb[2] = (short)0x3F80;
        }

        floatx4 acc0 = {0.f, 0.f, 0.f, 0.f};
        floatx4 acc1 = {0.f, 0.f, 0.f, 0.f};
        acc0 = __builtin_amdgcn_mfma_f32_16x16x32_bf16(a0, fb, acc0, 0, 0, 0);
        acc1 = __builtin_amdgcn_mfma_f32_16x16x32_bf16(a1, fb, acc1, 0, 0, 0);

        float partial = 0.f;
        #pragma unroll
        for (int q = 0; q < 4; ++q) {
            partial += fmaxf(acc0[q], 0.f) * w2v0[q];
            partial += fmaxf(acc1[q], 0.f) * w2v1[q];
        }
        partial += __shfl_xor(partial, 16, 64);
        partial += __shfl_xor(partial, 32, 64);

        float val = 1.0f / (1.0f + __expf(-(partial + bias2)));
        if (g == 0 && valid) out[e] = val;
    }
}

extern "C" void kernel_launch(void* const* d_in, const int* in_sizes, int n_in,
                              void* d_out, int out_size, void* d_ws, size_t ws_size,
                              hipStream_t stream) {
    const float* nt_emb = (const float*)d_in[0];
    const char*  ei     = (const char*)d_in[1];
    const float* lm     = (const float*)d_in[2];
    const float* W1     = (const float*)d_in[3];
    const float* b1     = (const float*)d_in[4];
    const float* W2     = (const float*)d_in[5];
    const float* b2     = (const float*)d_in[6];
    float* out = (float*)d_out;

    long long E = (long long)in_sizes[1] / 2;   // edge_index is [2, E]
    int N = in_sizes[2];                        // lm_mask is [N]

    size_t tableBytes = (size_t)N * 32;
    if (ws_size >= tableBytes) {
        short* T = (short*)d_ws;
        build_table<<<dim3((N + 255) / 256), dim3(256), 0, stream>>>(nt_emb, lm, T, N);
        lg_table_kernel<<<dim3(2048), dim3(256), 0, stream>>>(ei, T, W1, b1, W2, b2, out, E);
    } else {
        lg_kernel<<<dim3(2048), dim3(256), 0, stream>>>(nt_emb, ei, lm, W1, b1, W2, b2, out, E);
    }
}